// Round 6
// baseline (175.146 us; speedup 1.0000x reference)
//
#include <hip/hip_runtime.h>
#include <math.h>
#include <stdint.h>

#define B_ 4
#define N_ 250000
#define P_ 1000
#define G_ 32
#define C_ 81
#define RPN_BATCH 256
#define ROI_BATCH 128

#define ABLK 1024                                   // anchors per block
#define NBA ((N_ + ABLK - 1) / ABLK)                // 245

__device__ __forceinline__ float iou_one(float a0, float a1, float a2, float a3,
                                         float areaA,
                                         float b0, float b1, float b2, float b3) {
    float ltx = fmaxf(a0, b0), lty = fmaxf(a1, b1);
    float rbx = fminf(a2, b2), rby = fminf(a3, b3);
    float w = fmaxf(rbx - ltx, 0.f), h = fmaxf(rby - lty, 0.f);
    float inter = w * h;
    float areaB = (b2 - b0) * (b3 - b1);
    return inter / (areaA + areaB - inter + 1e-6f);
}

__device__ __forceinline__ unsigned long long shfl_xor_u64(unsigned long long v, int m) {
    unsigned lo = (unsigned)v, hi = (unsigned)(v >> 32);
    lo = __shfl_xor(lo, m);
    hi = __shfl_xor(hi, m);
    return ((unsigned long long)hi << 32) | lo;
}

__device__ __forceinline__ float smooth_l1(float x) {
    float ax = fabsf(x);
    return (ax < 1.f) ? 0.5f * x * x : ax - 0.5f;
}

// Kernel 1: labels + per-block pos/neg counts + per-(block,gt) best anchor.
// Wave w handles gts [8w,8w+8); gt coords via wave-uniform SGPR loads.
// Block (0,0) zero-inits sums/out/doneCnt (replaces memset dispatches).
__global__ void __launch_bounds__(256, 4) rpn_assign(
        const float* __restrict__ anchors, const float* __restrict__ gt_boxes,
        int8_t* __restrict__ labels, int* __restrict__ posCnt, int* __restrict__ negCnt,
        unsigned long long* __restrict__ blockBest,
        float* __restrict__ sums, unsigned* __restrict__ doneCnt,
        float* __restrict__ out, int out_size) {
    __shared__ float4 sA[ABLK];                 // 16 KB
    __shared__ unsigned char sPart[4][ABLK];    // 4 KB
    __shared__ int sCnt[8];

    int b = blockIdx.y, tid = threadIdx.x;
    int base = blockIdx.x * ABLK;

    if (blockIdx.x == 0 && b == 0) {
        if (tid < 8) sums[tid] = 0.f;
        if (tid < B_) doneCnt[tid] = 0u;
        for (int i = tid; i < out_size; i += 256) out[i] = 0.f;
    }

    for (int t = tid; t < ABLK; t += 256) {
        int ai = base + t;
        float4 v = make_float4(0.f, 0.f, 0.f, 0.f);
        if (ai < N_) v = ((const float4*)anchors)[ai];
        sA[t] = v;
    }
    __syncthreads();

    int lane = tid & 63, wave = tid >> 6;
    int waveu = __builtin_amdgcn_readfirstlane(wave);   // provably wave-uniform

    const float4* gt4 = (const float4*)gt_boxes + b * G_ + waveu * 8;
    float g0[8], g1[8], g2[8], g3[8], gae[8];
#pragma unroll
    for (int j = 0; j < 8; ++j) {
        float4 g = gt4[j];
        g0[j] = g.x; g1[j] = g.y; g2[j] = g.z; g3[j] = g.w;
        gae[j] = (g.z - g.x) * (g.w - g.y) + 1e-6f;
    }

    float bi[8], bd[8]; int bx[8];
#pragma unroll
    for (int j = 0; j < 8; ++j) { bi[j] = 0.f; bd[j] = 1.f; bx[j] = 0; }

    for (int k = 0; k < ABLK / 64; ++k) {
        int a = k * 64 + lane;
        float4 A = sA[a];
        float areaA = (A.z - A.x) * (A.w - A.y);
        int gidx = base + a;
        float acc03 = 1e30f, acc07 = 1e30f;
#pragma unroll
        for (int j = 0; j < 8; ++j) {
            float ltx = fmaxf(A.x, g0[j]), lty = fmaxf(A.y, g1[j]);
            float rbx = fminf(A.z, g2[j]), rby = fminf(A.w, g3[j]);
            float w = fmaxf(rbx - ltx, 0.f), h = fmaxf(rby - lty, 0.f);
            float inter = w * h;
            float d = (areaA + gae[j]) - inter;
            acc03 = fminf(acc03, fmaf(0.3f, d, -inter)); // >0 => iou<0.3
            acc07 = fminf(acc07, fmaf(0.7f, d, -inter)); // <0 => iou>0.7
            float p1 = inter * bd[j], p2 = bi[j] * d;
            if (p1 > p2) { bi[j] = inter; bd[j] = d; bx[j] = gidx; }
        }
        sPart[wave][a] = (unsigned char)(((acc07 < 0.f) ? 2 : 0) | ((acc03 > 0.f) ? 1 : 0));
    }

#pragma unroll
    for (int j = 0; j < 8; ++j) {
        float i_ = bi[j], d_ = bd[j]; int x_ = bx[j];
        for (int m = 32; m >= 1; m >>= 1) {
            float oi = __shfl_xor(i_, m), od = __shfl_xor(d_, m);
            int ox = __shfl_xor(x_, m);
            float pa = oi * d_, pb = i_ * od;
            bool take = (pa > pb) || (pa == pb && ox < x_);
            if (take) { i_ = oi; d_ = od; x_ = ox; }
        }
        if (lane == 0) {
            float iou = i_ / d_;
            unsigned long long pk =
                (((unsigned long long)__float_as_uint(iou)) << 32) |
                (unsigned)(0xFFFFFFFFu - (unsigned)x_);
            blockBest[((size_t)b * G_ + wave * 8 + j) * NBA + blockIdx.x] = pk;
        }
    }
    __syncthreads();

    unsigned u0 = ((const unsigned*)&sPart[0][0])[tid];
    unsigned u1 = ((const unsigned*)&sPart[1][0])[tid];
    unsigned u2 = ((const unsigned*)&sPart[2][0])[tid];
    unsigned u3 = ((const unsigned*)&sPart[3][0])[tid];
    unsigned andb = u0 & u1 & u2 & u3;
    unsigned orb  = u0 | u1 | u2 | u3;
    int gbase = base + tid * 4;
    unsigned outw = 0; int cp = 0, cn = 0;
#pragma unroll
    for (int j = 0; j < 4; ++j) {
        int above = (orb >> (8 * j + 1)) & 1;
        int below = (andb >> (8 * j)) & 1;
        int lab = above ? 1 : (below ? 0 : -1);
        if (gbase + j < N_) { cp += (lab == 1); cn += (lab == 0); }
        outw |= ((unsigned)(unsigned char)(char)lab) << (8 * j);
    }
    if (gbase < N_)
        ((unsigned*)labels)[(((size_t)b * N_ + base) >> 2) + tid] = outw;

    for (int m = 32; m >= 1; m >>= 1) { cp += __shfl_xor(cp, m); cn += __shfl_xor(cn, m); }
    if (lane == 0) { sCnt[wave] = cp; sCnt[4 + wave] = cn; }
    __syncthreads();
    if (tid == 0) {
        posCnt[b * NBA + blockIdx.x] = sCnt[0] + sCnt[1] + sCnt[2] + sCnt[3];
        negCnt[b * NBA + blockIdx.x] = sCnt[4] + sCnt[5] + sCnt[6] + sCnt[7];
    }
}

// Kernel 2: per-gt global winner -> promote + LDS count adjust + block-count scan.
__global__ void __launch_bounds__(256) rpn_promote_scan(
        const unsigned long long* __restrict__ blockBest, int8_t* __restrict__ labels,
        int* __restrict__ posCnt, int* __restrict__ negCnt,
        int* __restrict__ totPos, int* __restrict__ totNeg) {
    int b = blockIdx.x, tid = threadIdx.x;
    __shared__ int sp[256], sn[256];
    __shared__ unsigned wIdx[G_];

    sp[tid] = (tid < NBA) ? posCnt[b * NBA + tid] : 0;
    sn[tid] = (tid < NBA) ? negCnt[b * NBA + tid] : 0;

    int g = tid >> 3, sub = tid & 7;   // 32 gts x 8 threads
    unsigned long long v = 0;
    for (int j = sub; j < NBA; j += 8) {
        unsigned long long x = blockBest[((size_t)b * G_ + g) * NBA + j];
        if (x > v) v = x;
    }
    for (int m = 4; m >= 1; m >>= 1) {
        unsigned long long o = shfl_xor_u64(v, m);
        if (o > v) v = o;
    }
    if (sub == 0) wIdx[g] = 0xFFFFFFFFu - (unsigned)(v & 0xFFFFFFFFull);
    __syncthreads();
    if (tid < G_) {
        unsigned w = wIdx[tid];
        bool first = true;
        for (int j = 0; j < tid; ++j) if (wIdx[j] == w) first = false;
        if (first) {
            size_t li = (size_t)b * N_ + w;
            int8_t old = labels[li];
            labels[li] = 1;
            int blk = (int)(w / ABLK);
            if (old != 1) atomicAdd(&sp[blk], 1);
            if (old == 0) atomicAdd(&sn[blk], -1);
        }
    }
    __syncthreads();

    int vp = sp[tid], vn = sn[tid];
    for (int off = 1; off < 256; off <<= 1) {
        int tp = 0, tn = 0;
        if (tid >= off) { tp = sp[tid - off]; tn = sn[tid - off]; }
        __syncthreads();
        sp[tid] += tp; sn[tid] += tn;
        __syncthreads();
    }
    if (tid < NBA) {
        posCnt[b * NBA + tid] = sp[tid] - vp;
        negCnt[b * NBA + tid] = sn[tid] - vn;
    }
    if (tid == 0) { totPos[b] = sp[255]; totNeg[b] = sn[255]; }
}

// Kernel 3 (fused): blockIdx.x < NBA -> RPN sample/BCE/reg; the LAST-finishing
// sample block per batch (device-scope ticket) adds the RPN epilogue to out.
// blockIdx.x == NBA -> full detection loss for batch (256-thread variant),
// added to out directly.
__global__ void __launch_bounds__(256) rpn_sample_det(
        const int8_t* __restrict__ labels, const float* __restrict__ rpn_scores,
        const float* __restrict__ rpn_deltas, const float* __restrict__ anchors,
        const float* __restrict__ gt_boxes,
        const float* __restrict__ cls_scores, const float* __restrict__ bbox_deltas,
        const float* __restrict__ proposals, const int* __restrict__ gt_labels,
        const int* __restrict__ posBase, const int* __restrict__ negBase,
        const int* __restrict__ totPos, const int* __restrict__ totNeg,
        float* __restrict__ sums, unsigned* __restrict__ doneCnt,
        float* __restrict__ out) {
    int b = blockIdx.y, tid = threadIdx.x;
    int lane = tid & 63, wave = tid >> 6;

    if (blockIdx.x == NBA) {
        // ---------------- detection loss, 256 threads ----------------
        __shared__ float sgt[G_ * 4];
        __shared__ int sgl[G_];
        __shared__ short sassign[1024];
        __shared__ unsigned char sargm[1024];
        __shared__ int sw4[4];
        __shared__ int ssamp[ROI_BATCH];
        __shared__ float cacc[4], racc[4];
        if (tid < G_ * 4) sgt[tid] = gt_boxes[b * G_ * 4 + tid];
        if (tid < G_) sgl[tid] = gt_labels[b * G_ + tid];
        __syncthreads();

        for (int k = 0; k < 4; ++k) {
            int p = tid + k * 256;
            if (p < P_) {
                float4 A = ((const float4*)proposals)[b * P_ + p];
                float areaA = (A.z - A.x) * (A.w - A.y);
                float best = -1.f; int am = 0;
#pragma unroll 8
                for (int g = 0; g < G_; ++g) {
                    float iou = iou_one(A.x, A.y, A.z, A.w, areaA,
                                        sgt[g * 4], sgt[g * 4 + 1], sgt[g * 4 + 2], sgt[g * 4 + 3]);
                    if (iou > best) { best = iou; am = g; }
                }
                sassign[p] = (best >= 0.5f) ? (short)sgl[am] : (short)0;
                sargm[p] = (unsigned char)am;
            }
        }
        __syncthreads();

        // sampling via rank arithmetic, CH=4 contiguous per thread
        int c0 = tid * 4, cnt = 0;
#pragma unroll
        for (int k = 0; k < 4; ++k) {
            int p = c0 + k;
            if (p < P_ && sassign[p] > 0) cnt++;
        }
        int inc = cnt;
        for (int off = 1; off < 64; off <<= 1) {
            int v = __shfl_up(inc, off);
            if (lane >= off) inc += v;
        }
        if (lane == 63) sw4[wave] = inc;
        __syncthreads();
        int basew = 0, total = 0;
        for (int w = 0; w < 4; ++w) { if (w < wave) basew += sw4[w]; total += sw4[w]; }
        int prefix = basew + inc - cnt;
        int npos_kept = min(total, ROI_BATCH / 4);
        int nneg_total = P_ - total;
#pragma unroll
        for (int k = 0; k < 4; ++k) {
            int p = c0 + k;
            if (p >= P_) break;
            int slot;
            if (sassign[p] > 0) {
                slot = (prefix < ROI_BATCH / 4) ? prefix
                     : npos_kept + nneg_total + (prefix - ROI_BATCH / 4);
                prefix++;
            } else {
                slot = npos_kept + (p - prefix);
            }
            if (slot < ROI_BATCH) ssamp[slot] = p;
        }
        int np_det = npos_kept + max(0, ROI_BATCH - npos_kept - nneg_total);
        __syncthreads();

        // 4 waves x 32 ROIs, wave-parallel softmax
        float clsv = 0.f, regv = 0.f;
        for (int k = 0; k < 32; ++k) {
            int r = wave * 32 + k;
            int s = ssamp[r];
            int t = sassign[s];
            const float* row = cls_scores + ((size_t)(b * P_ + s)) * C_;
            float v1 = row[lane];
            float v2 = (lane < C_ - 64) ? row[64 + lane] : -INFINITY;
            float m = fmaxf(v1, v2);
            for (int mm = 32; mm >= 1; mm >>= 1) m = fmaxf(m, __shfl_xor(m, mm));
            float se = expf(v1 - m) + ((lane < C_ - 64) ? expf(v2 - m) : 0.f);
            for (int mm = 32; mm >= 1; mm >>= 1) se += __shfl_xor(se, mm);
            if (lane == 0) {
                clsv += -(row[t] - m - logf(se));
                if (t > 0) {
                    int g = sargm[s];
                    float4 A = ((const float4*)proposals)[b * P_ + s];
                    float t0 = sgt[g * 4], t1 = sgt[g * 4 + 1];
                    float t2 = sgt[g * 4 + 2], t3 = sgt[g * 4 + 3];
                    float wa = A.z - A.x, ha = A.w - A.y;
                    float xa = A.x + 0.5f * wa, ya = A.y + 0.5f * ha;
                    float wt = t2 - t0, ht = t3 - t1;
                    float xt = t0 + 0.5f * wt, yt = t1 + 0.5f * ht;
                    const float4 pd = *(const float4*)(bbox_deltas +
                            ((size_t)(b * P_ + s)) * (4 * C_) + 4 * t);
                    regv += smooth_l1(pd.x - (xt - xa) / wa) + smooth_l1(pd.y - (yt - ya) / ha) +
                            smooth_l1(pd.z - logf(wt / wa + 1e-6f)) + smooth_l1(pd.w - logf(ht / ha + 1e-6f));
                }
            }
        }
        if (lane == 0) { cacc[wave] = clsv; racc[wave] = regv; }
        __syncthreads();
        if (tid == 0) {
            float cs = cacc[0] + cacc[1] + cacc[2] + cacc[3];
            float rs = racc[0] + racc[1] + racc[2] + racc[3];
            float cls = cs / (float)ROI_BATCH;
            float reg = (np_det > 0) ? rs / fmaxf((float)np_det * 4.f, 1.f) : 0.f;
            atomicAdd(out, cls + reg);
        }
        return;
    }

    // ---------------- RPN sample path ----------------
    int base = blockIdx.x * ABLK;
    __shared__ float sg[G_ * 4];
    __shared__ int swP[4], swN[4];
    __shared__ float sred[8];
    if (tid < G_ * 4) sg[tid] = gt_boxes[b * G_ * 4 + tid];

    int gbase = base + tid * 4;
    unsigned word = 0xFFFFFFFFu;
    if (gbase < N_)
        word = ((const unsigned*)labels)[(((size_t)b * N_ + base) >> 2) + tid];
    int lab[4]; int cntP = 0, cntN = 0;
#pragma unroll
    for (int j = 0; j < 4; ++j) {
        lab[j] = (int)(char)((word >> (8 * j)) & 0xFF);
        cntP += (lab[j] == 1); cntN += (lab[j] == 0);
    }
    int ip = cntP, inn = cntN;
    for (int off = 1; off < 64; off <<= 1) {
        int vp = __shfl_up(ip, off), vn = __shfl_up(inn, off);
        if (lane >= off) { ip += vp; inn += vn; }
    }
    if (lane == 63) { swP[wave] = ip; swN[wave] = inn; }
    __syncthreads();
    int bP = 0, bN = 0;
    for (int w = 0; w < wave; ++w) { bP += swP[w]; bN += swN[w]; }
    int pP = posBase[b * NBA + blockIdx.x] + bP + ip - cntP;
    int pN = negBase[b * NBA + blockIdx.x] + bN + inn - cntN;

    int npos = min(totPos[b], RPN_BATCH / 2);
    int negQ = RPN_BATCH - npos;

    float bce = 0.f, regv = 0.f;
#pragma unroll
    for (int j = 0; j < 4; ++j) {
        int i = gbase + j;
        if (i >= N_) break;
        if (lab[j] == 1) {
            int r = pP++;
            if (r < RPN_BATCH / 2) {
                float l = rpn_scores[(size_t)b * N_ + i];
                bce += fmaxf(l, 0.f) - l + log1pf(expf(-fabsf(l)));
                float4 A = ((const float4*)anchors)[i];
                float areaA = (A.z - A.x) * (A.w - A.y);
                float best = -1.f; int am = 0;
                for (int g = 0; g < G_; ++g) {
                    float iou = iou_one(A.x, A.y, A.z, A.w, areaA,
                                        sg[g * 4], sg[g * 4 + 1], sg[g * 4 + 2], sg[g * 4 + 3]);
                    if (iou > best) { best = iou; am = g; }
                }
                float t0 = sg[am * 4], t1 = sg[am * 4 + 1], t2 = sg[am * 4 + 2], t3 = sg[am * 4 + 3];
                float wa = A.z - A.x, ha = A.w - A.y;
                float xa = A.x + 0.5f * wa, ya = A.y + 0.5f * ha;
                float wt = t2 - t0, ht = t3 - t1;
                float xt = t0 + 0.5f * wt, yt = t1 + 0.5f * ht;
                float4 D = ((const float4*)rpn_deltas)[(size_t)b * N_ + i];
                regv += smooth_l1(D.x - (xt - xa) / wa) + smooth_l1(D.y - (yt - ya) / ha) +
                        smooth_l1(D.z - logf(wt / wa + 1e-6f)) + smooth_l1(D.w - logf(ht / ha + 1e-6f));
            }
        } else if (lab[j] == 0) {
            int r = pN++;
            if (r < negQ) {
                float l = rpn_scores[(size_t)b * N_ + i];
                bce += fmaxf(l, 0.f) + log1pf(expf(-fabsf(l)));
            }
        }
    }
    for (int m = 32; m >= 1; m >>= 1) { bce += __shfl_xor(bce, m); regv += __shfl_xor(regv, m); }
    if (lane == 0) { sred[wave] = bce; sred[4 + wave] = regv; }
    __syncthreads();
    if (tid == 0) {
        float sb = sred[0] + sred[1] + sred[2] + sred[3];
        float sr = sred[4] + sred[5] + sred[6] + sred[7];
        if (sb != 0.f) atomicAdd(&sums[b], sb);
        if (sr != 0.f) atomicAdd(&sums[4 + b], sr);
        __threadfence();                                   // publish before ticket
        unsigned prev = atomicAdd(&doneCnt[b], 1u);
        if (prev == NBA - 1) {                             // last sample block of batch b
            float csum = atomicAdd(&sums[b], 0.f);         // coherent device-scope read
            float rsum = atomicAdd(&sums[4 + b], 0.f);
            int rnp = min(totPos[b], RPN_BATCH / 2);
            int kneg = min(totNeg[b], RPN_BATCH - rnp);
            float rcls = csum / fmaxf((float)(rnp + kneg), 1.f);
            float rreg = (rnp > 0) ? rsum / fmaxf((float)rnp * 4.f, 1.f) : 0.f;
            atomicAdd(out, rcls + rreg);
        }
    }
}

extern "C" void kernel_launch(void* const* d_in, const int* in_sizes, int n_in,
                              void* d_out, int out_size, void* d_ws, size_t ws_size,
                              hipStream_t stream) {
    const float* rpn_scores  = (const float*)d_in[0];
    const float* rpn_deltas  = (const float*)d_in[1];
    const float* cls_scores  = (const float*)d_in[2];
    const float* bbox_deltas = (const float*)d_in[3];
    const float* anchors     = (const float*)d_in[4];
    const float* proposals   = (const float*)d_in[5];
    const float* gt_boxes    = (const float*)d_in[6];
    const int*   gt_labels   = (const int*)d_in[7];
    float* out = (float*)d_out;

    char* ws = (char*)d_ws;
    size_t off = 0;
    auto alloc = [&](size_t bytes) -> char* {
        size_t o = (off + 255) & ~(size_t)255;
        off = o + bytes;
        return ws + o;
    };
    int8_t* labels = (int8_t*)alloc((size_t)B_ * N_);
    unsigned long long* blockBest = (unsigned long long*)alloc((size_t)B_ * G_ * NBA * 8);
    int* posCnt = (int*)alloc((size_t)B_ * NBA * 4);
    int* negCnt = (int*)alloc((size_t)B_ * NBA * 4);
    int* totPos = (int*)alloc(B_ * 4);
    int* totNeg = (int*)alloc(B_ * 4);
    float* sums = (float*)alloc(8 * 4);        // clsSum[4] | regSum[4]
    unsigned* doneCnt = (unsigned*)alloc(B_ * 4);

    rpn_assign<<<dim3(NBA, B_), 256, 0, stream>>>(anchors, gt_boxes, labels,
                                                  posCnt, negCnt, blockBest,
                                                  sums, doneCnt, out, out_size);
    rpn_promote_scan<<<B_, 256, 0, stream>>>(blockBest, labels, posCnt, negCnt,
                                             totPos, totNeg);
    rpn_sample_det<<<dim3(NBA + 1, B_), 256, 0, stream>>>(
        labels, rpn_scores, rpn_deltas, anchors, gt_boxes,
        cls_scores, bbox_deltas, proposals, gt_labels,
        posCnt, negCnt, totPos, totNeg, sums, doneCnt, out);
}

// Round 7
// 161.374 us; speedup vs baseline: 1.0853x; 1.0853x over previous
//
#include <hip/hip_runtime.h>
#include <math.h>
#include <stdint.h>

#define B_ 4
#define N_ 250000
#define P_ 1000
#define G_ 32
#define C_ 81
#define RPN_BATCH 256
#define ROI_BATCH 128

#define ABLK 1024                                   // anchors per block
#define NBA ((N_ + ABLK - 1) / ABLK)                // 245

__device__ __forceinline__ float iou_one(float a0, float a1, float a2, float a3,
                                         float areaA,
                                         float b0, float b1, float b2, float b3) {
    float ltx = fmaxf(a0, b0), lty = fmaxf(a1, b1);
    float rbx = fminf(a2, b2), rby = fminf(a3, b3);
    float w = fmaxf(rbx - ltx, 0.f), h = fmaxf(rby - lty, 0.f);
    float inter = w * h;
    float areaB = (b2 - b0) * (b3 - b1);
    return inter / (areaA + areaB - inter + 1e-6f);
}

__device__ __forceinline__ unsigned long long shfl_xor_u64(unsigned long long v, int m) {
    unsigned lo = (unsigned)v, hi = (unsigned)(v >> 32);
    lo = __shfl_xor(lo, m);
    hi = __shfl_xor(hi, m);
    return ((unsigned long long)hi << 32) | lo;
}

__device__ __forceinline__ float smooth_l1(float x) {
    float ax = fabsf(x);
    return (ax < 1.f) ? 0.5f * x * x : ax - 0.5f;
}

// Kernel 1: labels + per-block pos/neg counts + per-(block,gt) best anchor.
__global__ void __launch_bounds__(256, 4) rpn_assign(
        const float* __restrict__ anchors, const float* __restrict__ gt_boxes,
        int8_t* __restrict__ labels, int* __restrict__ posCnt, int* __restrict__ negCnt,
        unsigned long long* __restrict__ blockBest,
        float* __restrict__ sums, float* __restrict__ out, int out_size) {
    __shared__ float4 sA[ABLK];                 // 16 KB
    __shared__ unsigned char sPart[4][ABLK];    // 4 KB
    __shared__ int sCnt[8];

    int b = blockIdx.y, tid = threadIdx.x;
    int base = blockIdx.x * ABLK;

    if (blockIdx.x == 0 && b == 0) {
        if (tid < 8) sums[tid] = 0.f;
        for (int i = tid; i < out_size; i += 256) out[i] = 0.f;
    }

    for (int t = tid; t < ABLK; t += 256) {
        int ai = base + t;
        float4 v = make_float4(0.f, 0.f, 0.f, 0.f);
        if (ai < N_) v = ((const float4*)anchors)[ai];
        sA[t] = v;
    }
    __syncthreads();

    int lane = tid & 63, wave = tid >> 6;
    int waveu = __builtin_amdgcn_readfirstlane(wave);   // provably wave-uniform

    const float4* gt4 = (const float4*)gt_boxes + b * G_ + waveu * 8;
    float g0[8], g1[8], g2[8], g3[8], gae[8];
#pragma unroll
    for (int j = 0; j < 8; ++j) {
        float4 g = gt4[j];
        g0[j] = g.x; g1[j] = g.y; g2[j] = g.z; g3[j] = g.w;
        gae[j] = (g.z - g.x) * (g.w - g.y) + 1e-6f;
    }

    float bi[8], bd[8]; int bx[8];
#pragma unroll
    for (int j = 0; j < 8; ++j) { bi[j] = 0.f; bd[j] = 1.f; bx[j] = 0; }

    for (int k = 0; k < ABLK / 64; ++k) {
        int a = k * 64 + lane;
        float4 A = sA[a];
        float areaA = (A.z - A.x) * (A.w - A.y);
        int gidx = base + a;
        float acc03 = 1e30f, acc07 = 1e30f;
#pragma unroll
        for (int j = 0; j < 8; ++j) {
            float ltx = fmaxf(A.x, g0[j]), lty = fmaxf(A.y, g1[j]);
            float rbx = fminf(A.z, g2[j]), rby = fminf(A.w, g3[j]);
            float w = fmaxf(rbx - ltx, 0.f), h = fmaxf(rby - lty, 0.f);
            float inter = w * h;
            float d = (areaA + gae[j]) - inter;
            acc03 = fminf(acc03, fmaf(0.3f, d, -inter)); // >0 => iou<0.3
            acc07 = fminf(acc07, fmaf(0.7f, d, -inter)); // <0 => iou>0.7
            float p1 = inter * bd[j], p2 = bi[j] * d;
            if (p1 > p2) { bi[j] = inter; bd[j] = d; bx[j] = gidx; }
        }
        sPart[wave][a] = (unsigned char)(((acc07 < 0.f) ? 2 : 0) | ((acc03 > 0.f) ? 1 : 0));
    }

#pragma unroll
    for (int j = 0; j < 8; ++j) {
        float i_ = bi[j], d_ = bd[j]; int x_ = bx[j];
        for (int m = 32; m >= 1; m >>= 1) {
            float oi = __shfl_xor(i_, m), od = __shfl_xor(d_, m);
            int ox = __shfl_xor(x_, m);
            float pa = oi * d_, pb = i_ * od;
            bool take = (pa > pb) || (pa == pb && ox < x_);
            if (take) { i_ = oi; d_ = od; x_ = ox; }
        }
        if (lane == 0) {
            float iou = i_ / d_;
            unsigned long long pk =
                (((unsigned long long)__float_as_uint(iou)) << 32) |
                (unsigned)(0xFFFFFFFFu - (unsigned)x_);
            blockBest[((size_t)b * G_ + wave * 8 + j) * NBA + blockIdx.x] = pk;
        }
    }
    __syncthreads();

    unsigned u0 = ((const unsigned*)&sPart[0][0])[tid];
    unsigned u1 = ((const unsigned*)&sPart[1][0])[tid];
    unsigned u2 = ((const unsigned*)&sPart[2][0])[tid];
    unsigned u3 = ((const unsigned*)&sPart[3][0])[tid];
    unsigned andb = u0 & u1 & u2 & u3;
    unsigned orb  = u0 | u1 | u2 | u3;
    int gbase = base + tid * 4;
    unsigned outw = 0; int cp = 0, cn = 0;
#pragma unroll
    for (int j = 0; j < 4; ++j) {
        int above = (orb >> (8 * j + 1)) & 1;
        int below = (andb >> (8 * j)) & 1;
        int lab = above ? 1 : (below ? 0 : -1);
        if (gbase + j < N_) { cp += (lab == 1); cn += (lab == 0); }
        outw |= ((unsigned)(unsigned char)(char)lab) << (8 * j);
    }
    if (gbase < N_)
        ((unsigned*)labels)[(((size_t)b * N_ + base) >> 2) + tid] = outw;

    for (int m = 32; m >= 1; m >>= 1) { cp += __shfl_xor(cp, m); cn += __shfl_xor(cn, m); }
    if (lane == 0) { sCnt[wave] = cp; sCnt[4 + wave] = cn; }
    __syncthreads();
    if (tid == 0) {
        posCnt[b * NBA + blockIdx.x] = sCnt[0] + sCnt[1] + sCnt[2] + sCnt[3];
        negCnt[b * NBA + blockIdx.x] = sCnt[4] + sCnt[5] + sCnt[6] + sCnt[7];
    }
}

// Kernel 2: per-gt global winner -> promote + LDS count adjust + block-count scan.
__global__ void __launch_bounds__(256) rpn_promote_scan(
        const unsigned long long* __restrict__ blockBest, int8_t* __restrict__ labels,
        int* __restrict__ posCnt, int* __restrict__ negCnt,
        int* __restrict__ totPos, int* __restrict__ totNeg) {
    int b = blockIdx.x, tid = threadIdx.x;
    __shared__ int sp[256], sn[256];
    __shared__ unsigned wIdx[G_];

    sp[tid] = (tid < NBA) ? posCnt[b * NBA + tid] : 0;
    sn[tid] = (tid < NBA) ? negCnt[b * NBA + tid] : 0;

    int g = tid >> 3, sub = tid & 7;   // 32 gts x 8 threads
    unsigned long long v = 0;
    for (int j = sub; j < NBA; j += 8) {
        unsigned long long x = blockBest[((size_t)b * G_ + g) * NBA + j];
        if (x > v) v = x;
    }
    for (int m = 4; m >= 1; m >>= 1) {
        unsigned long long o = shfl_xor_u64(v, m);
        if (o > v) v = o;
    }
    if (sub == 0) wIdx[g] = 0xFFFFFFFFu - (unsigned)(v & 0xFFFFFFFFull);
    __syncthreads();
    if (tid < G_) {
        unsigned w = wIdx[tid];
        bool first = true;
        for (int j = 0; j < tid; ++j) if (wIdx[j] == w) first = false;
        if (first) {
            size_t li = (size_t)b * N_ + w;
            int8_t old = labels[li];
            labels[li] = 1;
            int blk = (int)(w / ABLK);
            if (old != 1) atomicAdd(&sp[blk], 1);
            if (old == 0) atomicAdd(&sn[blk], -1);
        }
    }
    __syncthreads();

    int vp = sp[tid], vn = sn[tid];
    for (int off = 1; off < 256; off <<= 1) {
        int tp = 0, tn = 0;
        if (tid >= off) { tp = sp[tid - off]; tn = sn[tid - off]; }
        __syncthreads();
        sp[tid] += tp; sn[tid] += tn;
        __syncthreads();
    }
    if (tid < NBA) {
        posCnt[b * NBA + tid] = sp[tid] - vp;
        negCnt[b * NBA + tid] = sn[tid] - vn;
    }
    if (tid == 0) { totPos[b] = sp[255]; totNeg[b] = sn[255]; }
}

// Kernel 3: ranks -> kept samples; BCE sum; reg loss for kept positives.
__global__ void __launch_bounds__(256) rpn_sample(
        const int8_t* __restrict__ labels, const float* __restrict__ rpn_scores,
        const float* __restrict__ rpn_deltas, const float* __restrict__ anchors,
        const float* __restrict__ gt_boxes,
        const int* __restrict__ posBase, const int* __restrict__ negBase,
        const int* __restrict__ totPos, float* __restrict__ sums) {
    int b = blockIdx.y, tid = threadIdx.x;
    int base = blockIdx.x * ABLK;
    __shared__ float sg[G_ * 4];
    __shared__ int swP[4], swN[4];
    __shared__ float sred[8];
    if (tid < G_ * 4) sg[tid] = gt_boxes[b * G_ * 4 + tid];

    int gbase = base + tid * 4;
    unsigned word = 0xFFFFFFFFu;
    if (gbase < N_)
        word = ((const unsigned*)labels)[(((size_t)b * N_ + base) >> 2) + tid];
    int lab[4]; int cntP = 0, cntN = 0;
#pragma unroll
    for (int j = 0; j < 4; ++j) {
        lab[j] = (int)(char)((word >> (8 * j)) & 0xFF);
        cntP += (lab[j] == 1); cntN += (lab[j] == 0);
    }
    int lane = tid & 63, wave = tid >> 6;
    int ip = cntP, inn = cntN;
    for (int off = 1; off < 64; off <<= 1) {
        int vp = __shfl_up(ip, off), vn = __shfl_up(inn, off);
        if (lane >= off) { ip += vp; inn += vn; }
    }
    if (lane == 63) { swP[wave] = ip; swN[wave] = inn; }
    __syncthreads();
    int bP = 0, bN = 0;
    for (int w = 0; w < wave; ++w) { bP += swP[w]; bN += swN[w]; }
    int pP = posBase[b * NBA + blockIdx.x] + bP + ip - cntP;
    int pN = negBase[b * NBA + blockIdx.x] + bN + inn - cntN;

    int npos = min(totPos[b], RPN_BATCH / 2);
    int negQ = RPN_BATCH - npos;

    float bce = 0.f, regv = 0.f;
#pragma unroll
    for (int j = 0; j < 4; ++j) {
        int i = gbase + j;
        if (i >= N_) break;
        if (lab[j] == 1) {
            int r = pP++;
            if (r < RPN_BATCH / 2) {
                float l = rpn_scores[(size_t)b * N_ + i];
                bce += fmaxf(l, 0.f) - l + log1pf(expf(-fabsf(l)));
                float4 A = ((const float4*)anchors)[i];
                float areaA = (A.z - A.x) * (A.w - A.y);
                float best = -1.f; int am = 0;
                for (int g = 0; g < G_; ++g) {
                    float iou = iou_one(A.x, A.y, A.z, A.w, areaA,
                                        sg[g * 4], sg[g * 4 + 1], sg[g * 4 + 2], sg[g * 4 + 3]);
                    if (iou > best) { best = iou; am = g; }
                }
                float t0 = sg[am * 4], t1 = sg[am * 4 + 1], t2 = sg[am * 4 + 2], t3 = sg[am * 4 + 3];
                float wa = A.z - A.x, ha = A.w - A.y;
                float xa = A.x + 0.5f * wa, ya = A.y + 0.5f * ha;
                float wt = t2 - t0, ht = t3 - t1;
                float xt = t0 + 0.5f * wt, yt = t1 + 0.5f * ht;
                float4 D = ((const float4*)rpn_deltas)[(size_t)b * N_ + i];
                regv += smooth_l1(D.x - (xt - xa) / wa) + smooth_l1(D.y - (yt - ya) / ha) +
                        smooth_l1(D.z - logf(wt / wa + 1e-6f)) + smooth_l1(D.w - logf(ht / ha + 1e-6f));
            }
        } else if (lab[j] == 0) {
            int r = pN++;
            if (r < negQ) {
                float l = rpn_scores[(size_t)b * N_ + i];
                bce += fmaxf(l, 0.f) + log1pf(expf(-fabsf(l)));
            }
        }
    }
    for (int m = 32; m >= 1; m >>= 1) { bce += __shfl_xor(bce, m); regv += __shfl_xor(regv, m); }
    if (lane == 0) { sred[wave] = bce; sred[4 + wave] = regv; }
    __syncthreads();
    if (tid == 0) {
        float sb = sred[0] + sred[1] + sred[2] + sred[3];
        float sr = sred[4] + sred[5] + sred[6] + sred[7];
        if (sb != 0.f) atomicAdd(&sums[b], sb);
        if (sr != 0.f) atomicAdd(&sums[4 + b], sr);
    }
}

// Kernel 4: detection loss + per-batch epilogue, 1024 threads/block.
// Phase 1: assign (1 proposal/thread). Phase 2: shfl-scan sampling.
// Phase 3: stage 128 sampled class rows into LDS with full MLP (16 waves x 8
// rows x 2 independent loads), wave-parallel softmax stats -> per-ROI m/logse,
// then ONE THREAD PER ROI computes cls (LDS only) + reg (128 parallel loads).
__global__ void __launch_bounds__(1024) det_all(
        const float* __restrict__ cls_scores, const float* __restrict__ bbox_deltas,
        const float* __restrict__ proposals, const float* __restrict__ gt_boxes,
        const int* __restrict__ gt_labels, const int* __restrict__ totPos,
        const int* __restrict__ totNeg, const float* __restrict__ sums,
        float* __restrict__ out) {
    int b = blockIdx.x, tid = threadIdx.x;
    int lane = tid & 63, wave = tid >> 6;
    __shared__ float sgt[G_ * 4];
    __shared__ int sgl[G_];
    __shared__ short sassign[P_];
    __shared__ unsigned char sargm[P_];
    __shared__ int sw[16];
    __shared__ int ssamp[ROI_BATCH];
    __shared__ float sRow[ROI_BATCH][C_];      // 41.5 KB staged class rows
    __shared__ float sM[ROI_BATCH], sLse[ROI_BATCH];
    __shared__ float cacc[2], racc[2];
    if (tid < G_ * 4) sgt[tid] = gt_boxes[b * G_ * 4 + tid];
    if (tid < G_) sgl[tid] = gt_labels[b * G_ + tid];
    __syncthreads();

    // phase 1: assign
    int lab = 0;
    if (tid < P_) {
        float4 A = ((const float4*)proposals)[b * P_ + tid];
        float areaA = (A.z - A.x) * (A.w - A.y);
        float best = -1.f; int am = 0;
#pragma unroll 8
        for (int g = 0; g < G_; ++g) {
            float iou = iou_one(A.x, A.y, A.z, A.w, areaA,
                                sgt[g * 4], sgt[g * 4 + 1], sgt[g * 4 + 2], sgt[g * 4 + 3]);
            if (iou > best) { best = iou; am = g; }
        }
        lab = (best >= 0.5f) ? sgl[am] : 0;
        sassign[tid] = (short)lab;
        sargm[tid] = (unsigned char)am;
    }

    // phase 2: sampling ranks
    int cnt = (tid < P_ && lab > 0) ? 1 : 0;
    int inc = cnt;
    for (int off = 1; off < 64; off <<= 1) {
        int v = __shfl_up(inc, off);
        if (lane >= off) inc += v;
    }
    if (lane == 63) sw[wave] = inc;
    __syncthreads();
    int basew = 0, total = 0;
    for (int w = 0; w < 16; ++w) { if (w < wave) basew += sw[w]; total += sw[w]; }
    int prefix = basew + inc - cnt;
    int npos_kept = min(total, ROI_BATCH / 4);
    int nneg_total = P_ - total;
    if (tid < P_) {
        int slot;
        if (lab > 0)
            slot = (prefix < ROI_BATCH / 4) ? prefix
                 : npos_kept + nneg_total + (prefix - ROI_BATCH / 4);
        else
            slot = npos_kept + (tid - prefix);
        if (slot < ROI_BATCH) ssamp[slot] = tid;
    }
    int np_det = npos_kept + max(0, ROI_BATCH - npos_kept - nneg_total);
    __syncthreads();

    // phase 3a: stage class rows (16 waves x 8 rows, independent loads)
    for (int k = 0; k < 8; ++k) {
        int r = wave * 8 + k;
        int s = ssamp[r];
        const float* row = cls_scores + ((size_t)(b * P_ + s)) * C_;
        float v1 = row[lane];
        sRow[r][lane] = v1;
        if (lane < C_ - 64) sRow[r][64 + lane] = row[64 + lane];
    }
    __syncthreads();

    // phase 3b: wave-parallel softmax stats from LDS
    for (int k = 0; k < 8; ++k) {
        int r = wave * 8 + k;
        float v1 = sRow[r][lane];
        float v2 = (lane < C_ - 64) ? sRow[r][64 + lane] : -INFINITY;
        float m = fmaxf(v1, v2);
        for (int mm = 32; mm >= 1; mm >>= 1) m = fmaxf(m, __shfl_xor(m, mm));
        float se = expf(v1 - m) + ((lane < C_ - 64) ? expf(v2 - m) : 0.f);
        for (int mm = 32; mm >= 1; mm >>= 1) se += __shfl_xor(se, mm);
        if (lane == 0) { sM[r] = m; sLse[r] = logf(se); }
    }
    __syncthreads();

    // phase 3c: one thread per ROI — cls from LDS, reg with parallel loads
    float clsv = 0.f, regv = 0.f;
    if (tid < ROI_BATCH) {
        int s = ssamp[tid];
        int t = sassign[s];
        clsv = -(sRow[tid][t] - sM[tid] - sLse[tid]);
        if (t > 0) {
            int g = sargm[s];
            float4 A = ((const float4*)proposals)[b * P_ + s];
            float t0 = sgt[g * 4], t1 = sgt[g * 4 + 1];
            float t2 = sgt[g * 4 + 2], t3 = sgt[g * 4 + 3];
            float wa = A.z - A.x, ha = A.w - A.y;
            float xa = A.x + 0.5f * wa, ya = A.y + 0.5f * ha;
            float wt = t2 - t0, ht = t3 - t1;
            float xt = t0 + 0.5f * wt, yt = t1 + 0.5f * ht;
            const float4 pd = *(const float4*)(bbox_deltas +
                    ((size_t)(b * P_ + s)) * (4 * C_) + 4 * t);
            regv = smooth_l1(pd.x - (xt - xa) / wa) + smooth_l1(pd.y - (yt - ya) / ha) +
                   smooth_l1(pd.z - logf(wt / wa + 1e-6f)) + smooth_l1(pd.w - logf(ht / ha + 1e-6f));
        }
    }
    if (tid < 128) {
        for (int m = 32; m >= 1; m >>= 1) {
            clsv += __shfl_xor(clsv, m);
            regv += __shfl_xor(regv, m);
        }
        if (lane == 0) { cacc[wave] = clsv; racc[wave] = regv; }
    }
    __syncthreads();
    if (tid == 0) {
        float cls = (cacc[0] + cacc[1]) / (float)ROI_BATCH;
        float reg = (np_det > 0) ? (racc[0] + racc[1]) / fmaxf((float)np_det * 4.f, 1.f) : 0.f;
        int rnp = min(totPos[b], RPN_BATCH / 2);
        int kneg = min(totNeg[b], RPN_BATCH - rnp);
        float rcls = sums[b] / fmaxf((float)(rnp + kneg), 1.f);
        float rreg = (rnp > 0) ? sums[4 + b] / fmaxf((float)rnp * 4.f, 1.f) : 0.f;
        atomicAdd(out, cls + reg + rcls + rreg);
    }
}

extern "C" void kernel_launch(void* const* d_in, const int* in_sizes, int n_in,
                              void* d_out, int out_size, void* d_ws, size_t ws_size,
                              hipStream_t stream) {
    const float* rpn_scores  = (const float*)d_in[0];
    const float* rpn_deltas  = (const float*)d_in[1];
    const float* cls_scores  = (const float*)d_in[2];
    const float* bbox_deltas = (const float*)d_in[3];
    const float* anchors     = (const float*)d_in[4];
    const float* proposals   = (const float*)d_in[5];
    const float* gt_boxes    = (const float*)d_in[6];
    const int*   gt_labels   = (const int*)d_in[7];
    float* out = (float*)d_out;

    char* ws = (char*)d_ws;
    size_t off = 0;
    auto alloc = [&](size_t bytes) -> char* {
        size_t o = (off + 255) & ~(size_t)255;
        off = o + bytes;
        return ws + o;
    };
    int8_t* labels = (int8_t*)alloc((size_t)B_ * N_);
    unsigned long long* blockBest = (unsigned long long*)alloc((size_t)B_ * G_ * NBA * 8);
    int* posCnt = (int*)alloc((size_t)B_ * NBA * 4);
    int* negCnt = (int*)alloc((size_t)B_ * NBA * 4);
    int* totPos = (int*)alloc(B_ * 4);
    int* totNeg = (int*)alloc(B_ * 4);
    float* sums = (float*)alloc(8 * 4);    // clsSum[4] | regSum[4]

    rpn_assign<<<dim3(NBA, B_), 256, 0, stream>>>(anchors, gt_boxes, labels,
                                                  posCnt, negCnt, blockBest,
                                                  sums, out, out_size);
    rpn_promote_scan<<<B_, 256, 0, stream>>>(blockBest, labels, posCnt, negCnt,
                                             totPos, totNeg);
    rpn_sample<<<dim3(NBA, B_), 256, 0, stream>>>(labels, rpn_scores, rpn_deltas,
                                                  anchors, gt_boxes, posCnt, negCnt,
                                                  totPos, sums);
    det_all<<<B_, 1024, 0, stream>>>(cls_scores, bbox_deltas, proposals, gt_boxes,
                                     gt_labels, totPos, totNeg, sums, out);
}